// Round 1
// baseline (487.978 us; speedup 1.0000x reference)
//
#include <hip/hip_runtime.h>
#include <cstdint>

#define B 16
#define H 128
#define W 128
#define NC 80
#define PB (H*W*NC)          // 1310720 per-batch candidates
#define K 100
#define CAP 16384            // candidate buffer per batch
#define THRESH 0.95f
#define NBINS 4096
#define LISTCAP 512

// static device scratch: 16*16384*8 = 2 MB + counters
__device__ unsigned long long g_cand[B * CAP];
__device__ int g_counts[B];

__device__ __forceinline__ float sigmoidf(float x) {
    return 1.0f / (1.0f + expf(-x));
}

__global__ void zero_counts_kernel() {
    if (threadIdx.x < B) g_counts[threadIdx.x] = 0;
}

// Stage A: sigmoid + 3x3 peak NMS (exact, in sigmoid space) + compaction.
__global__ __launch_bounds__(256) void peak_kernel(const float* __restrict__ cls) {
    int gid = blockIdx.x * 256 + threadIdx.x;              // < B*PB = 20,971,520
    unsigned ub = (unsigned)gid / (unsigned)PB;            // batch (block-uniform)
    unsigned ib = (unsigned)gid - ub * (unsigned)PB;       // index within batch
    unsigned sidx = ib / (unsigned)NC;                     // y*W + x
    unsigned x = sidx & (W - 1);
    unsigned y = sidx >> 7;

    float vc = cls[gid];
    const float NI = -__builtin_inff();
    bool xl = (x > 0), xr = (x < W - 1);
    bool yu = (y > 0), yd = (y < H - 1);

    float m = vc;
    // same row
    m = fmaxf(m, xl ? cls[gid - NC] : NI);
    m = fmaxf(m, xr ? cls[gid + NC] : NI);
    // row above
    {
        float a = yu ? cls[gid - W * NC] : NI;
        float b0 = (yu && xl) ? cls[gid - W * NC - NC] : NI;
        float c0 = (yu && xr) ? cls[gid - W * NC + NC] : NI;
        m = fmaxf(m, fmaxf(a, fmaxf(b0, c0)));
    }
    // row below
    {
        float a = yd ? cls[gid + W * NC] : NI;
        float b0 = (yd && xl) ? cls[gid + W * NC - NC] : NI;
        float c0 = (yd && xr) ? cls[gid + W * NC + NC] : NI;
        m = fmaxf(m, fmaxf(a, fmaxf(b0, c0)));
    }

    float sc = sigmoidf(vc);
    float sm = sigmoidf(m);          // max(sigmoid(win)) == sigmoid(max(win)) (monotone rounding)
    bool cand = (sc == sm) && (sc > THRESH);

    unsigned long long mask = __ballot(cand);
    if (mask) {
        int lane = threadIdx.x & 63;
        int leader = __ffsll((unsigned long long)mask) - 1;
        int cnt = __popcll(mask);
        int base = 0;
        if (lane == leader) base = atomicAdd(&g_counts[ub], cnt);
        base = __shfl(base, leader);
        if (cand) {
            int off = __popcll(mask & ((1ull << lane) - 1ull));
            int slot = base + off;
            if (slot < CAP) {
                // key: descending by value, then ascending by flat index
                unsigned long long key =
                    ((unsigned long long)__float_as_uint(sc) << 32) |
                    (unsigned long long)(0xFFFFFFFFu - ib);
                g_cand[ub * CAP + slot] = key;
            }
        }
    }
}

// Stage B: per-batch top-K (histogram cutoff -> collect -> bitonic sort -> decode)
__global__ __launch_bounds__(256) void topk_kernel(const float* __restrict__ dxy,
                                                   const float* __restrict__ swh,
                                                   float* __restrict__ out) {
    const int b = blockIdx.x;
    const int tid = threadIdx.x;
    __shared__ int hist[NBINS];
    __shared__ int csum[256];
    __shared__ unsigned long long list[LISTCAP];
    __shared__ int lcount;
    __shared__ int kstar;

    int n = g_counts[b];
    if (n > CAP) n = CAP;
    const unsigned long long* cb = g_cand + (size_t)b * CAP;

    for (int i = tid; i < NBINS; i += 256) hist[i] = 0;
    if (tid == 0) lcount = 0;
    __syncthreads();

    const float SCALE = (float)NBINS / (1.0f - THRESH);   // 81920
    for (int i = tid; i < n; i += 256) {
        float v = __uint_as_float((unsigned)(cb[i] >> 32));
        int bin = (int)((v - THRESH) * SCALE);
        bin = bin < 0 ? 0 : (bin > NBINS - 1 ? NBINS - 1 : bin);
        atomicAdd(&hist[bin], 1);
    }
    __syncthreads();

    int s = 0;
    for (int j = 0; j < NBINS / 256; j++) s += hist[tid * (NBINS / 256) + j];
    csum[tid] = s;
    __syncthreads();

    if (tid == 0) {
        int acc = 0;
        int chunk = 255;
        for (; chunk >= 0; chunk--) {
            if (acc + csum[chunk] >= K) break;
            acc += csum[chunk];
        }
        int ks = 0;
        if (chunk >= 0) {
            int j = NBINS / 256 - 1;
            for (; j >= 0; j--) {
                acc += hist[chunk * (NBINS / 256) + j];
                if (acc >= K) break;
            }
            if (j < 0) j = 0;
            ks = chunk * (NBINS / 256) + j;
        }
        kstar = ks;
    }
    __syncthreads();

    int ks = kstar;
    for (int i = tid; i < n; i += 256) {
        unsigned long long key = cb[i];
        float v = __uint_as_float((unsigned)(key >> 32));
        int bin = (int)((v - THRESH) * SCALE);
        bin = bin < 0 ? 0 : (bin > NBINS - 1 ? NBINS - 1 : bin);
        if (bin >= ks) {
            int p = atomicAdd(&lcount, 1);
            if (p < LISTCAP) list[p] = key;
        }
    }
    __syncthreads();
    int M = lcount < LISTCAP ? lcount : LISTCAP;
    for (int i = tid; i < LISTCAP; i += 256)
        if (i >= M) list[i] = 0ull;
    __syncthreads();

    // bitonic sort ascending over LISTCAP elements (keys distinct or 0-padded)
    for (int kk = 2; kk <= LISTCAP; kk <<= 1) {
        for (int j = kk >> 1; j > 0; j >>= 1) {
            for (int t = tid; t < LISTCAP; t += 256) {
                int ixj = t ^ j;
                if (ixj > t) {
                    bool up = ((t & kk) == 0);
                    unsigned long long a = list[t];
                    unsigned long long c = list[ixj];
                    if ((a > c) == up) { list[t] = c; list[ixj] = a; }
                }
            }
            __syncthreads();
        }
    }

    if (tid < K) {
        unsigned long long key = list[LISTCAP - 1 - tid];   // rank tid (descending)
        float conf = __uint_as_float((unsigned)(key >> 32));
        unsigned ib = 0xFFFFFFFFu - (unsigned)(key & 0xFFFFFFFFu);
        unsigned cls_i = ib % (unsigned)NC;
        unsigned sidx = ib / (unsigned)NC;
        unsigned xg = sidx & (W - 1);
        unsigned yg = sidx >> 7;

        size_t goff = ((size_t)b * (H * W) + sidx) * 2;
        float dx = dxy[goff], dy = dxy[goff + 1];
        float sw = swh[goff], sh = swh[goff + 1];

        float xs = (float)xg + dx;
        float ys = (float)yg + dy;
        float hw = sw * 0.5f;
        float hh = sh * 0.5f;
        const float invW = 1.0f / (float)W;   // /128 is exact (power of 2)
        const float invH = 1.0f / (float)H;
        float x1 = (xs - hw) * invW;
        float y1 = (ys - hh) * invH;
        float x2 = (xs + hw) * invW;
        float y2 = (ys + hh) * invH;

        int r = b * K + tid;
        out[r * 4 + 0] = x1;
        out[r * 4 + 1] = y1;
        out[r * 4 + 2] = x2;
        out[r * 4 + 3] = y2;
        out[B * K * 4 + r] = conf;            // confi
        out[B * K * 4 + B * K + r] = (float)cls_i;  // classes
    }
}

extern "C" void kernel_launch(void* const* d_in, const int* in_sizes, int n_in,
                              void* d_out, int out_size, void* d_ws, size_t ws_size,
                              hipStream_t stream) {
    const float* cls = (const float*)d_in[0];
    const float* dxy = (const float*)d_in[1];
    const float* swh = (const float*)d_in[2];
    float* out = (float*)d_out;

    zero_counts_kernel<<<1, 64, 0, stream>>>();
    int total = B * PB;
    peak_kernel<<<total / 256, 256, 0, stream>>>(cls);
    topk_kernel<<<B, 256, 0, stream>>>(dxy, swh, out);
}

// Round 2
// 171.620 us; speedup vs baseline: 2.8434x; 2.8434x over previous
//
#include <hip/hip_runtime.h>
#include <cstdint>

#define B 16
#define H 128
#define W 128
#define NC 80
#define PB (H*W*NC)
#define K 100
#define CAP 16384
#define THRESH 0.95f
#define NBINS 4096
#define LISTCAP 512
#define TY 16
#define CG 5              // class groups of 16
#define YT (H/TY)         // 8 y-tiles

__device__ unsigned long long g_cand[B * CAP];
__device__ int g_counts[B * 16];   // one cache line per counter

__device__ __forceinline__ float sigmoidf(float x) {
    return 1.0f / (1.0f + expf(-x));
}
__device__ __forceinline__ float4 f4max3(float4 a, float4 b, float4 c) {
    float4 r;
    r.x = fmaxf(a.x, fmaxf(b.x, c.x));
    r.y = fmaxf(a.y, fmaxf(b.y, c.y));
    r.z = fmaxf(a.z, fmaxf(b.z, c.z));
    r.w = fmaxf(a.w, fmaxf(b.w, c.w));
    return r;
}

__global__ void zero_counts_kernel() {
    if (threadIdx.x < B * 16) g_counts[threadIdx.x] = 0;
}

// Stage A: fused sigmoid + 3x3 peak NMS + compaction.
// Block = (batch, y-tile of TY rows, 16-class group). Thread = (x, float4 of classes).
// Separable max: horizontal via LDS row (double-buffered), vertical via register ring.
__global__ __launch_bounds__(512) void peak_kernel(const float* __restrict__ cls) {
    const int blk = blockIdx.x;                 // 0 .. B*YT*CG-1
    const int b   = blk / (YT * CG);
    const int rem = blk - b * (YT * CG);
    const int yt  = rem / CG;
    const int cg  = rem - yt * CG;
    const int tid = threadIdx.x;
    const int c4  = tid & 3;                    // float4 slot within 16-class group
    const int x   = tid >> 2;                   // 0..127
    const int y0  = yt * TY;
    const int cbase = cg * 16 + c4 * 4;         // class offset (16B aligned)

    __shared__ float4 row[2][128 * 4];          // 2 x 8 KB

    const float NI = -__builtin_inff();
    const float4 NEG = make_float4(NI, NI, NI, NI);
    const float* bp = cls + (size_t)b * PB;

    float4 hm_prev = NEG, hm_curr = NEG, v_curr = NEG;
    float4 r_pend = (y0 >= 1)
        ? *(const float4*)(bp + ((size_t)(y0 - 1) * W + x) * NC + cbase) : NEG;

    int buf = 0;
    for (int j = 0; j <= TY + 1; ++j) {
        const int yi = y0 - 1 + j;              // row being h-maxed this iter
        const int yn = yi + 1;                  // row to prefetch
        const bool yiv = (yi >= 0) & (yi < H);

        float4 r_next = NEG;
        if (j <= TY && yn < H)                  // prefetch: latency overlaps this iter
            r_next = *(const float4*)(bp + ((size_t)yn * W + x) * NC + cbase);

        if (yiv) row[buf][x * 4 + c4] = r_pend;
        __syncthreads();

        float4 hm_next = NEG;
        if (yiv) {
            float4 L = (x > 0)   ? row[buf][(x - 1) * 4 + c4] : NEG;
            float4 R = (x < 127) ? row[buf][(x + 1) * 4 + c4] : NEG;
            hm_next = f4max3(L, r_pend, R);
        }

        if (j >= 2) {
            const int yo = yi - 1;              // output row, in [y0, y0+TY-1]
            float4 vm4 = f4max3(hm_prev, hm_curr, hm_next);
            float vv[4] = { v_curr.x, v_curr.y, v_curr.z, v_curr.w };
            float mm[4] = { vm4.x, vm4.y, vm4.z, vm4.w };
            #pragma unroll
            for (int c = 0; c < 4; ++c) {
                float v = vv[c], vm = mm[c];
                // logit-space prefilter: sigmoid(2.9)<0.95; 1e-3 band covers
                // worst-case sigmoid rounding collisions (window ~1.5e-5 at logit 5.7)
                if (v > 2.9f && (vm - v) <= 1e-3f) {
                    float sc = sigmoidf(v);
                    float sm = sigmoidf(vm);    // = max(sigmoid(window)), monotone
                    if (sc == sm && sc > THRESH) {
                        unsigned ib = ((unsigned)(yo * W + x)) * NC + cbase + c;
                        unsigned long long key =
                            ((unsigned long long)__float_as_uint(sc) << 32) |
                            (unsigned long long)(0xFFFFFFFFu - ib);
                        int slot = atomicAdd(&g_counts[b * 16], 1);
                        if (slot < CAP) g_cand[b * CAP + slot] = key;
                    }
                }
            }
        }

        hm_prev = hm_curr; hm_curr = hm_next; v_curr = r_pend; r_pend = r_next;
        buf ^= 1;
    }
}

// Stage B: per-batch exact top-K (histogram cutoff -> collect -> rank-by-count -> decode)
__global__ __launch_bounds__(256) void topk_kernel(const float* __restrict__ dxy,
                                                   const float* __restrict__ swh,
                                                   float* __restrict__ out) {
    const int b = blockIdx.x;
    const int tid = threadIdx.x;
    __shared__ int hist[NBINS];
    __shared__ int csum[256];
    __shared__ unsigned long long list[LISTCAP];
    __shared__ int lcount;
    __shared__ int kstar;

    int n = g_counts[b * 16];
    if (n > CAP) n = CAP;
    const unsigned long long* cb = g_cand + (size_t)b * CAP;

    for (int i = tid; i < NBINS; i += 256) hist[i] = 0;
    if (tid == 0) lcount = 0;
    __syncthreads();

    const float SCALE = (float)NBINS / (1.0f - THRESH);
    for (int i = tid; i < n; i += 256) {
        float v = __uint_as_float((unsigned)(cb[i] >> 32));
        int bin = (int)((v - THRESH) * SCALE);
        bin = bin < 0 ? 0 : (bin > NBINS - 1 ? NBINS - 1 : bin);
        atomicAdd(&hist[bin], 1);
    }
    __syncthreads();

    int s = 0;
    for (int j = 0; j < NBINS / 256; j++) s += hist[tid * (NBINS / 256) + j];
    csum[tid] = s;
    __syncthreads();

    if (tid == 0) {
        int acc = 0;
        int chunk = 255;
        for (; chunk >= 0; chunk--) {
            if (acc + csum[chunk] >= K) break;
            acc += csum[chunk];
        }
        int ks = 0;
        if (chunk >= 0) {
            int j = NBINS / 256 - 1;
            for (; j >= 0; j--) {
                acc += hist[chunk * (NBINS / 256) + j];
                if (acc >= K) break;
            }
            if (j < 0) j = 0;
            ks = chunk * (NBINS / 256) + j;
        }
        kstar = ks;
    }
    __syncthreads();

    const int ks = kstar;
    for (int i = tid; i < n; i += 256) {
        unsigned long long key = cb[i];
        float v = __uint_as_float((unsigned)(key >> 32));
        int bin = (int)((v - THRESH) * SCALE);
        bin = bin < 0 ? 0 : (bin > NBINS - 1 ? NBINS - 1 : bin);
        if (bin >= ks) {
            int p = atomicAdd(&lcount, 1);
            if (p < LISTCAP) list[p] = key;
        }
    }
    __syncthreads();
    const int M = lcount < LISTCAP ? lcount : LISTCAP;

    // exact rank by counting (keys are distinct: low 32 bits unique per batch)
    for (int i = tid; i < M; i += 256) {
        unsigned long long key = list[i];
        int rank = 0;
        for (int j = 0; j < M; j++) rank += (list[j] > key);
        if (rank < K) {
            float conf = __uint_as_float((unsigned)(key >> 32));
            unsigned ib = 0xFFFFFFFFu - (unsigned)(key & 0xFFFFFFFFu);
            unsigned cls_i = ib % (unsigned)NC;
            unsigned sidx = ib / (unsigned)NC;
            unsigned xg = sidx & (W - 1);
            unsigned yg = sidx >> 7;

            size_t goff = ((size_t)b * (H * W) + sidx) * 2;
            float dx = dxy[goff], dy = dxy[goff + 1];
            float sw = swh[goff], sh = swh[goff + 1];

            float xs = (float)xg + dx;
            float ys = (float)yg + dy;
            float hw = sw * 0.5f;
            float hh = sh * 0.5f;
            const float invW = 1.0f / (float)W;
            const float invH = 1.0f / (float)H;

            int r = b * K + rank;
            out[r * 4 + 0] = (xs - hw) * invW;
            out[r * 4 + 1] = (ys - hh) * invH;
            out[r * 4 + 2] = (xs + hw) * invW;
            out[r * 4 + 3] = (ys + hh) * invH;
            out[B * K * 4 + r] = conf;
            out[B * K * 4 + B * K + r] = (float)cls_i;
        }
    }
}

extern "C" void kernel_launch(void* const* d_in, const int* in_sizes, int n_in,
                              void* d_out, int out_size, void* d_ws, size_t ws_size,
                              hipStream_t stream) {
    const float* cls = (const float*)d_in[0];
    const float* dxy = (const float*)d_in[1];
    const float* swh = (const float*)d_in[2];
    float* out = (float*)d_out;

    zero_counts_kernel<<<1, 256, 0, stream>>>();
    peak_kernel<<<B * YT * CG, 512, 0, stream>>>(cls);
    topk_kernel<<<B, 256, 0, stream>>>(dxy, swh, out);
}

// Round 3
// 166.478 us; speedup vs baseline: 2.9312x; 1.0309x over previous
//
#include <hip/hip_runtime.h>
#include <cstdint>

#define B 16
#define H 128
#define W 128
#define NC 80
#define PB (H*W*NC)
#define K 100
#define CAP 16384
#define THRESH 0.95f
#define NBINS 4096
#define LISTCAP 512
#define TY 16            // rows per wave-tile
#define TX 16            // cols per wave-tile
#define YT (H/TY)        // 8
#define XT (W/TX)        // 8

__device__ unsigned long long g_cand[B * CAP];
__device__ int g_counts[B * 16] = {};   // zero at load; topk re-zeros after use

__device__ __forceinline__ float sigmoidf(float x) {
    return 1.0f / (1.0f + expf(-x));
}
__device__ __forceinline__ float4 f4max3(float4 a, float4 b, float4 c) {
    float4 r;
    r.x = fmaxf(a.x, fmaxf(b.x, c.x));
    r.y = fmaxf(a.y, fmaxf(b.y, c.y));
    r.z = fmaxf(a.z, fmaxf(b.z, c.z));
    r.w = fmaxf(a.w, fmaxf(b.w, c.w));
    return r;
}
__device__ __forceinline__ float4 shfl4(float4 v, int src) {
    float4 r;
    r.x = __shfl(v.x, src);
    r.y = __shfl(v.y, src);
    r.z = __shfl(v.z, src);
    r.w = __shfl(v.w, src);
    return r;
}

// Stage A: fused sigmoid + 3x3 peak NMS + compaction.
// One wave per (b, y-tile, x-tile, 16-class group). No LDS, no barriers.
// Horizontal max via lane shuffles (x±1 = lane±4); tile-edge columns via a
// predicated 8-lane global load (hits lines fetched by the adjacent tile).
__global__ __launch_bounds__(320) void peak_kernel(const float* __restrict__ cls) {
    const int b    = blockIdx.x >> 6;          // grid = 16*8*8 = 1024
    const int yt   = (blockIdx.x >> 3) & 7;
    const int xt   = blockIdx.x & 7;
    const int cg   = threadIdx.x >> 6;         // wave id = class group (0..4)
    const int lane = threadIdx.x & 63;
    const int c4   = lane & 3;
    const int xl   = lane >> 2;                // 0..15
    const int x    = xt * TX + xl;
    const int y0   = yt * TY;
    const int cbase = cg * 16 + c4 * 4;

    const float NI = -__builtin_inff();
    const float4 NEG = make_float4(NI, NI, NI, NI);
    const float* bp = cls + (size_t)b * PB;

    const bool isL = (xl == 0), isR = (xl == TX - 1);
    const int  xn  = isL ? x - 1 : x + 1;      // neighbor column for edge lanes
    const bool ev  = (isL | isR) & (xn >= 0) & (xn < W);

    const int lsrcL = (lane - 4) & 63;
    const int lsrcR = (lane + 4) & 63;

    // pipeline registers: rows j, j+1, j+2  (j-row = y0-1+j)
    float4 mA, eA, mB, eB, mC, eC;

    auto loadRow = [&](int j, float4& m, float4& e) {
        const int y = y0 - 1 + j;
        const bool yv = (y >= 0) & (y < H);
        m = yv ? *(const float4*)(bp + ((size_t)y * W + x) * NC + cbase) : NEG;
        e = (yv & ev) ? *(const float4*)(bp + ((size_t)y * W + xn) * NC + cbase) : NEG;
    };

    loadRow(0, mA, eA);
    loadRow(1, mB, eB);

    float4 hm_prev = NEG, hm_curr = NEG, v_prev = NEG;

    #pragma unroll
    for (int j = 0; j < TY + 2; ++j) {
        if (j + 2 < TY + 2) loadRow(j + 2, mC, eC);
        else { mC = NEG; eC = NEG; }

        // horizontal 3-max of row j
        float4 L = shfl4(mA, lsrcL);
        float4 R = shfl4(mA, lsrcR);
        if (isL) L = eA;
        if (isR) R = eA;
        float4 hm_next = f4max3(L, mA, R);

        if (j >= 2) {
            const int yo = y0 + j - 2;         // output row
            float4 vm4 = f4max3(hm_prev, hm_curr, hm_next);
            float vv[4] = { v_prev.x, v_prev.y, v_prev.z, v_prev.w };
            float mm[4] = { vm4.x, vm4.y, vm4.z, vm4.w };
            #pragma unroll
            for (int c = 0; c < 4; ++c) {
                float v = vv[c], vm = mm[c];
                // logit-space prefilter: sigmoid(2.9)<0.95; 1e-3 band covers
                // worst-case sigmoid rounding collisions (window ~1.5e-5)
                if (v > 2.9f && (vm - v) <= 1e-3f) {
                    float sc = sigmoidf(v);
                    float sm = sigmoidf(vm);   // = max(sigmoid(window)), monotone
                    if (sc == sm && sc > THRESH) {
                        unsigned ib = ((unsigned)(yo * W + x)) * NC + cbase + c;
                        unsigned long long key =
                            ((unsigned long long)__float_as_uint(sc) << 32) |
                            (unsigned long long)(0xFFFFFFFFu - ib);
                        int slot = atomicAdd(&g_counts[b * 16], 1);
                        if (slot < CAP) g_cand[b * CAP + slot] = key;
                    }
                }
            }
        }

        hm_prev = hm_curr; hm_curr = hm_next; v_prev = mA;
        mA = mB; eA = eB; mB = mC; eB = eC;
    }
}

// Stage B: per-batch exact top-K (histogram cutoff -> collect -> rank-by-count -> decode)
__global__ __launch_bounds__(256) void topk_kernel(const float* __restrict__ dxy,
                                                   const float* __restrict__ swh,
                                                   float* __restrict__ out) {
    const int b = blockIdx.x;
    const int tid = threadIdx.x;
    __shared__ int hist[NBINS];
    __shared__ int csum[256];
    __shared__ unsigned long long list[LISTCAP];
    __shared__ int lcount;
    __shared__ int kstar;

    int n = g_counts[b * 16];
    if (n > CAP) n = CAP;
    const unsigned long long* cb = g_cand + (size_t)b * CAP;

    for (int i = tid; i < NBINS; i += 256) hist[i] = 0;
    if (tid == 0) lcount = 0;
    __syncthreads();

    const float SCALE = (float)NBINS / (1.0f - THRESH);
    for (int i = tid; i < n; i += 256) {
        float v = __uint_as_float((unsigned)(cb[i] >> 32));
        int bin = (int)((v - THRESH) * SCALE);
        bin = bin < 0 ? 0 : (bin > NBINS - 1 ? NBINS - 1 : bin);
        atomicAdd(&hist[bin], 1);
    }
    __syncthreads();

    int s = 0;
    for (int j = 0; j < NBINS / 256; j++) s += hist[tid * (NBINS / 256) + j];
    csum[tid] = s;
    __syncthreads();

    if (tid == 0) {
        int acc = 0;
        int chunk = 255;
        for (; chunk >= 0; chunk--) {
            if (acc + csum[chunk] >= K) break;
            acc += csum[chunk];
        }
        int ks = 0;
        if (chunk >= 0) {
            int j = NBINS / 256 - 1;
            for (; j >= 0; j--) {
                acc += hist[chunk * (NBINS / 256) + j];
                if (acc >= K) break;
            }
            if (j < 0) j = 0;
            ks = chunk * (NBINS / 256) + j;
        }
        kstar = ks;
    }
    __syncthreads();

    const int ks = kstar;
    for (int i = tid; i < n; i += 256) {
        unsigned long long key = cb[i];
        float v = __uint_as_float((unsigned)(key >> 32));
        int bin = (int)((v - THRESH) * SCALE);
        bin = bin < 0 ? 0 : (bin > NBINS - 1 ? NBINS - 1 : bin);
        if (bin >= ks) {
            int p = atomicAdd(&lcount, 1);
            if (p < LISTCAP) list[p] = key;
        }
    }
    __syncthreads();
    const int M = lcount < LISTCAP ? lcount : LISTCAP;

    // exact rank by counting (keys distinct: low 32 bits unique per batch)
    for (int i = tid; i < M; i += 256) {
        unsigned long long key = list[i];
        int rank = 0;
        for (int j = 0; j < M; j++) rank += (list[j] > key);
        if (rank < K) {
            float conf = __uint_as_float((unsigned)(key >> 32));
            unsigned ib = 0xFFFFFFFFu - (unsigned)(key & 0xFFFFFFFFu);
            unsigned cls_i = ib % (unsigned)NC;
            unsigned sidx = ib / (unsigned)NC;
            unsigned xg = sidx & (W - 1);
            unsigned yg = sidx >> 7;

            size_t goff = ((size_t)b * (H * W) + sidx) * 2;
            float dx = dxy[goff], dy = dxy[goff + 1];
            float sw = swh[goff], sh = swh[goff + 1];

            float xs = (float)xg + dx;
            float ys = (float)yg + dy;
            float hw = sw * 0.5f;
            float hh = sh * 0.5f;
            const float invW = 1.0f / (float)W;
            const float invH = 1.0f / (float)H;

            int r = b * K + rank;
            out[r * 4 + 0] = (xs - hw) * invW;
            out[r * 4 + 1] = (ys - hh) * invH;
            out[r * 4 + 2] = (xs + hw) * invW;
            out[r * 4 + 3] = (ys + hh) * invH;
            out[B * K * 4 + r] = conf;
            out[B * K * 4 + B * K + r] = (float)cls_i;
        }
    }

    __syncthreads();
    if (tid == 0) g_counts[b * 16] = 0;   // reset for next call (single writer)
}

extern "C" void kernel_launch(void* const* d_in, const int* in_sizes, int n_in,
                              void* d_out, int out_size, void* d_ws, size_t ws_size,
                              hipStream_t stream) {
    const float* cls = (const float*)d_in[0];
    const float* dxy = (const float*)d_in[1];
    const float* swh = (const float*)d_in[2];
    float* out = (float*)d_out;

    peak_kernel<<<B * YT * XT, 320, 0, stream>>>(cls);
    topk_kernel<<<B, 256, 0, stream>>>(dxy, swh, out);
}